// Round 12
// baseline (100.008 us; speedup 1.0000x reference)
//
#include <hip/hip_runtime.h>
#include <math.h>
#include <stdint.h>

// Problem constants (FPModule: knn-interpolate + 2-layer MLP)
#define Bn    4
#define Nn    2048
#define Mn    8192
#define CIN   256
#define CSKIP 128
#define HID   256
#define COUT  128
#define KTOT  384   // CIN + CSKIP

// 1-D point buckets over x
#define PB    256
#define PDX   0.03125f          // 2^-5: bucket edges GLOX + c*PDX exact in f32
#define GLOX  -4.0f
// query sort: 128 x-buckets x 4 radius classes
#define QXB   128
#define QDX   0.0625f
#define QNB   (QXB * 4)

typedef short bf16x8 __attribute__((ext_vector_type(8)));
typedef float f32x16 __attribute__((ext_vector_type(16)));

__device__ __forceinline__ ushort f2bf(float f) {
    union { float f; unsigned u; } v; v.f = f;
    return (ushort)((v.u + 0x7fffu + ((v.u >> 16) & 1u)) >> 16);   // RNE
}
__device__ __forceinline__ float bf2f(ushort u) {
    union { unsigned u; float f; } v; v.u = ((unsigned)u) << 16;
    return v.f;
}

// 5-op sorted-insert of key k into (kA <= kB <= kC), keeping 3 smallest.
// Order-independent: final triple = 3 smallest keys of the inserted multiset.
#define INSERT3(kA, kB, kC, k)            \
    do {                                  \
        const double _t = fmax(kA, k);    \
        kA = fmin(kA, k);                 \
        const double _u = fmax(kB, _t);   \
        kB = fmin(kB, _t);                \
        kC = fmin(kC, _u);                \
    } while (0)

__device__ __forceinline__ int pbucket(float v) {
    int c = (int)floorf((v - GLOX) / PDX);
    return min(max(c, 0), PB - 1);
}
__device__ __forceinline__ int qbucket(float v) {
    int c = (int)floorf((v - GLOX) / QDX);
    return min(max(c, 0), QXB - 1);
}

// ---------------------------------------------------------------------------
// Kernel 0: prep + sorts. Block roles:
//   [0,2048)      xb  = bf16(x)        (8192 x 256)
//   [2048,6144)   xsb = bf16(x_skip)   (32768 x 128)
//   [6144,6240)   W1T[n][k] = bf16(W1[k][n])
//   [6240,6272)   W2T[n][k] = bf16(W2[k][n])
//   [6272,6784)   tail: copy pos_skip + batch_skip into d_out
//   [6784,6788)   point sort (1 block/batch): bucket by x, hist/prefix/scatter
//                 -> spos4 = (2px,2py,2pz,pp) sorted, sidxp = orig idx,
//                 cellS[257]/batch.  pp via _rn ops (reference-exact); 2x exact.
//   [6788,6792)   query sort (1 block/batch): key = xbucket*4 + radius class
//                 -> qp4 = (x,y,z,qq) sorted, qoi = orig GLOBAL query idx.
//                 qq via _rn ops (reference-exact).
// ---------------------------------------------------------------------------
__global__ __launch_bounds__(256) void prep_sort(
    const float* __restrict__ x, const float* __restrict__ xs,
    const float* __restrict__ pos, const float* __restrict__ pos_skip,
    const float* __restrict__ W1, const float* __restrict__ W2,
    ushort* __restrict__ xb, ushort* __restrict__ xsb,
    ushort* __restrict__ W1T, ushort* __restrict__ W2T,
    float4* __restrict__ spos4, int* __restrict__ sidxp, int* __restrict__ cellS,
    float4* __restrict__ qp4, int* __restrict__ qoi,
    float* __restrict__ tail_dst)
{
    const int bid = blockIdx.x, tid = threadIdx.x;
    if (bid < 2048) {
        const int q = bid * 256 + tid;             // quads over 8192x256
        const int row = q >> 6, cq = (q & 63) * 4;
        const float4 v = *(const float4*)(x + (size_t)row * CIN + cq);
        ushort4 o; o.x = f2bf(v.x); o.y = f2bf(v.y); o.z = f2bf(v.z); o.w = f2bf(v.w);
        *(ushort4*)(xb + (size_t)row * CIN + cq) = o;
    } else if (bid < 6144) {
        const int q = (bid - 2048) * 256 + tid;    // quads over 32768x128
        const int row = q >> 5, cq = (q & 31) * 4;
        const float4 v = *(const float4*)(xs + (size_t)row * CSKIP + cq);
        ushort4 o; o.x = f2bf(v.x); o.y = f2bf(v.y); o.z = f2bf(v.z); o.w = f2bf(v.w);
        *(ushort4*)(xsb + (size_t)row * CSKIP + cq) = o;
    } else if (bid < 6240) {
        const int q = (bid - 6144) * 256 + tid;    // 24576 quads: n*96 + kq
        const int n = q / 96, kq = (q % 96) * 4;
        ushort4 o;
        o.x = f2bf(W1[(size_t)(kq + 0) * HID + n]);
        o.y = f2bf(W1[(size_t)(kq + 1) * HID + n]);
        o.z = f2bf(W1[(size_t)(kq + 2) * HID + n]);
        o.w = f2bf(W1[(size_t)(kq + 3) * HID + n]);
        *(ushort4*)(W1T + (size_t)n * KTOT + kq) = o;
    } else if (bid < 6272) {
        const int q = (bid - 6240) * 256 + tid;    // 8192 quads: n*64 + kq
        const int n = q >> 6, kq = (q & 63) * 4;
        ushort4 o;
        o.x = f2bf(W2[(size_t)(kq + 0) * COUT + n]);
        o.y = f2bf(W2[(size_t)(kq + 1) * COUT + n]);
        o.z = f2bf(W2[(size_t)(kq + 2) * COUT + n]);
        o.w = f2bf(W2[(size_t)(kq + 3) * COUT + n]);
        *(ushort4*)(W2T + (size_t)n * HID + kq) = o;
    } else if (bid < 6784) {
        const int i = (bid - 6272) * 256 + tid;
        const int nPos = Bn * Mn * 3;              // 98304
        if (i < nPos) tail_dst[i] = pos_skip[i];
        else          tail_dst[i] = (float)((i - nPos) >> 13);
    } else if (bid < 6788) {
        // ---- point sort, batch b ----
        __shared__ int hist[PB]; __shared__ int cst[PB + 1]; __shared__ int cnt[PB];
        const int b = bid - 6784;
        for (int c = tid; c < PB; c += 256) { hist[c] = 0; cnt[c] = 0; }
        __syncthreads();
        int cellv[8];
#pragma unroll
        for (int t = 0; t < 8; ++t) {
            const int i = tid * 8 + t;             // 0..2047
            const int c = pbucket(pos[((size_t)b * Nn + i) * 3]);
            cellv[t] = c;
            atomicAdd(&hist[c], 1);
        }
        __syncthreads();
        if (tid == 0) {
            int acc = 0;
            for (int c = 0; c < PB; ++c) { cst[c] = acc; acc += hist[c]; }
            cst[PB] = acc;
        }
        __syncthreads();
#pragma unroll
        for (int t = 0; t < 8; ++t) {
            const int i = tid * 8 + t;
            const float* p = pos + ((size_t)b * Nn + i) * 3;
            const float p0 = p[0], p1 = p[1], p2 = p[2];
            const float pp = __fadd_rn(__fadd_rn(__fmul_rn(p0, p0), __fmul_rn(p1, p1)),
                                       __fmul_rn(p2, p2));
            const int slot = cst[cellv[t]] + atomicAdd(&cnt[cellv[t]], 1);
            spos4[(size_t)b * Nn + slot] = make_float4(2.0f * p0, 2.0f * p1, 2.0f * p2, pp);
            sidxp[(size_t)b * Nn + slot] = i;
        }
        __syncthreads();
        for (int c = tid; c <= PB; c += 256) cellS[b * (PB + 1) + c] = cst[c];
    } else {
        // ---- query sort, batch b ----
        __shared__ int qh[QNB]; __shared__ int qst[QNB]; __shared__ int qcn[QNB];
        const int b = bid - 6788;
        for (int c = tid; c < QNB; c += 256) { qh[c] = 0; qcn[c] = 0; }
        __syncthreads();
        for (int t = 0; t < 32; ++t) {
            const int i = tid * 32 + t;            // 0..8191
            const float* p = pos_skip + ((size_t)b * Mn + i) * 3;
            const float qq = __fadd_rn(__fadd_rn(__fmul_rn(p[0], p[0]), __fmul_rn(p[1], p[1])),
                                       __fmul_rn(p[2], p[2]));
            const int cls = (qq < 2.0f) ? 0 : (qq < 4.0f) ? 1 : (qq < 8.0f) ? 2 : 3;
            atomicAdd(&qh[qbucket(p[0]) * 4 + cls], 1);
        }
        __syncthreads();
        if (tid == 0) {
            int acc = 0;
            for (int c = 0; c < QNB; ++c) { qst[c] = acc; acc += qh[c]; }
        }
        __syncthreads();
        for (int t = 0; t < 32; ++t) {
            const int i = tid * 32 + t;
            const float* p = pos_skip + ((size_t)b * Mn + i) * 3;
            const float p0 = p[0], p1 = p[1], p2 = p[2];
            const float qq = __fadd_rn(__fadd_rn(__fmul_rn(p0, p0), __fmul_rn(p1, p1)),
                                       __fmul_rn(p2, p2));
            const int cls = (qq < 2.0f) ? 0 : (qq < 4.0f) ? 1 : (qq < 8.0f) ? 2 : 3;
            const int key = qbucket(p0) * 4 + cls;
            const int slot = qst[key] + atomicAdd(&qcn[key], 1);
            qp4[(size_t)b * Mn + slot] = make_float4(p0, p1, p2, qq);
            qoi[(size_t)b * Mn + slot] = b * Mn + i;   // global query index
        }
    }
}

// ---------------------------------------------------------------------------
// Shared 128x128 bf16 MFMA tile (unchanged from R11).
// ---------------------------------------------------------------------------
__device__ __forceinline__ void gemm_acc128(
    const ushort* __restrict__ A, int lda,
    const ushort* __restrict__ BT, int ldb,
    int ksteps, long rowbase, long colbase, int tid,
    ushort* Ast, ushort* Bst, f32x16 acc[2][2])
{
    const int wave = tid >> 6, lane = tid & 63;
    const int wr = wave >> 1, wc = wave & 1;
    const int l31 = lane & 31, kc0 = lane >> 5;
    const int sr0 = tid >> 2;
    const int ss0 = tid & 3;
    const int ssw = ss0 ^ (sr0 & 3);

    uint4 ra0, ra1, rb0, rb1;
    ra0 = *(const uint4*)(A + (rowbase + sr0) * lda + ss0 * 8);
    ra1 = *(const uint4*)(A + (rowbase + sr0 + 64) * lda + ss0 * 8);
    rb0 = *(const uint4*)(BT + (colbase + sr0) * ldb + ss0 * 8);
    rb1 = *(const uint4*)(BT + (colbase + sr0 + 64) * ldb + ss0 * 8);

    for (int t = 0; t < ksteps; ++t) {
        __syncthreads();
        *(uint4*)&Ast[sr0 * 32 + (ssw << 3)]        = ra0;
        *(uint4*)&Ast[(sr0 + 64) * 32 + (ssw << 3)] = ra1;
        *(uint4*)&Bst[sr0 * 32 + (ssw << 3)]        = rb0;
        *(uint4*)&Bst[(sr0 + 64) * 32 + (ssw << 3)] = rb1;
        __syncthreads();
        if (t < ksteps - 1) {
            const int kt = (t + 1) * 32;
            ra0 = *(const uint4*)(A + (rowbase + sr0) * lda + kt + ss0 * 8);
            ra1 = *(const uint4*)(A + (rowbase + sr0 + 64) * lda + kt + ss0 * 8);
            rb0 = *(const uint4*)(BT + (colbase + sr0) * ldb + kt + ss0 * 8);
            rb1 = *(const uint4*)(BT + (colbase + sr0 + 64) * ldb + kt + ss0 * 8);
        }
#pragma unroll
        for (int s = 0; s < 2; ++s) {
            bf16x8 af[2], bq[2];
#pragma unroll
            for (int mf = 0; mf < 2; ++mf) {
                const int r = wr * 64 + mf * 32 + l31;
                af[mf] = *(const bf16x8*)&Ast[r * 32 + ((((s << 1) | kc0) ^ (r & 3)) << 3)];
            }
#pragma unroll
            for (int nf = 0; nf < 2; ++nf) {
                const int rn = wc * 64 + nf * 32 + l31;
                bq[nf] = *(const bf16x8*)&Bst[rn * 32 + ((((s << 1) | kc0) ^ (rn & 3)) << 3)];
            }
#pragma unroll
            for (int mf = 0; mf < 2; ++mf)
#pragma unroll
                for (int nf = 0; nf < 2; ++nf)
                    acc[mf][nf] = __builtin_amdgcn_mfma_f32_32x32x16_bf16(
                        af[mf], bq[nf], acc[mf][nf], 0, 0, 0);
        }
    }
}

// ---------------------------------------------------------------------------
// Kernel 1: Y = xb @ W1[:256] ; Z = xsb @ W1[256:]  (unchanged from R11)
// ---------------------------------------------------------------------------
__global__ __launch_bounds__(256) void yz_gemm(
    const ushort* __restrict__ xb, const ushort* __restrict__ xsb,
    const ushort* __restrict__ W1T,
    ushort* __restrict__ Y, ushort* __restrict__ Z)
{
    __shared__ ushort Ast[128 * 32];
    __shared__ ushort Bst[128 * 32];

    const int bid = blockIdx.x, tid = threadIdx.x;
    f32x16 acc[2][2];
#pragma unroll
    for (int i = 0; i < 2; ++i)
#pragma unroll
        for (int j = 0; j < 2; ++j)
#pragma unroll
            for (int e = 0; e < 16; ++e) acc[i][j][e] = 0.0f;

    const ushort* A; ushort* C;
    long rowbase, colbase; int lda, ksteps; const ushort* BT; int ldb = KTOT;
    if (bid < 128) {
        rowbase = (long)(bid >> 1) * 128; colbase = (long)(bid & 1) * 128;
        A = xb; lda = CIN; ksteps = CIN / 32; BT = W1T; C = Y;
    } else {
        const int cb = bid - 128;
        rowbase = (long)(cb >> 1) * 128; colbase = (long)(cb & 1) * 128;
        A = xsb; lda = CSKIP; ksteps = CSKIP / 32; BT = W1T + CIN; C = Z;
    }
    gemm_acc128(A, lda, BT, ldb, ksteps, rowbase, colbase, tid, Ast, Bst, acc);

    const int wave = tid >> 6, lane = tid & 63;
    const int wr = wave >> 1, wc = wave & 1;
    const int l31 = lane & 31, kc0 = lane >> 5;
#pragma unroll
    for (int mf = 0; mf < 2; ++mf)
#pragma unroll
        for (int nf = 0; nf < 2; ++nf) {
            const long col = colbase + wc * 64 + nf * 32 + l31;
#pragma unroll
            for (int e = 0; e < 16; ++e) {
                const int rl = wr * 64 + mf * 32 + (e & 3) + ((e >> 2) << 3) + (kc0 << 2);
                C[(rowbase + rl) * HID + col] = f2bf(acc[mf][nf][e]);
            }
        }
}

// ---------------------------------------------------------------------------
// Kernel 2: windowed KNN select + h-build. 2048 blocks x 256 thr.
// Block = 16 sorted-adjacent queries; scan contiguous x-window of sorted
// points, all 16 qloc lanes share each candidate (R7-coherent). Selection:
// f64 key = double(d) | orig_idx (lex (d,idx) == top_k order); d bit-identical
// to reference. Verify per query: d3 < (gap to scanned edge)^2 - 1e-3 (slab
// bound, edges exact f32, open at grid boundary); expand window on failure
// (incremental rescan; terminates at full range == brute force).
// h[origq] = relu(w0*Y[i0]+w1*Y[i1]+w2*Y[i2] + Z[origq] + b1)  (R11 math).
// ---------------------------------------------------------------------------
#define SCAN_RANGE(S, E)                                                        \
    for (int i = (S) + chunk; i < (E); i += 16) {                               \
        const float4 P = cp[i];                                                 \
        const float dot2 = __fadd_rn(__fadd_rn(__fmul_rn(q0, P.x),              \
                              __fmul_rn(q1, P.y)), __fmul_rn(q2, P.z));         \
        const float d = __fsub_rn(__fadd_rn(qq, P.w), dot2);                    \
        const double kk = __longlong_as_double(                                 \
            __double_as_longlong((double)d) | (long long)ci[i]);                \
        INSERT3(kA, kB, kC, kk);                                                \
    }

__global__ __launch_bounds__(256) void knn_win(
    const float4* __restrict__ spos4, const int* __restrict__ sidxp,
    const int* __restrict__ cellS,
    const float4* __restrict__ qp4, const int* __restrict__ qoi,
    const ushort* __restrict__ Y, const ushort* __restrict__ Z,
    const float* __restrict__ b1, ushort* __restrict__ h)
{
    __shared__ double sKey[16][3][17];
    __shared__ int    sIdx[16][3];
    __shared__ float  sRW[16][3];
    __shared__ int    sOrig[16];
    __shared__ float  sX[16], sQQ[16];
    __shared__ int    sOkAll;

    const int tid = threadIdx.x, qloc = tid & 15, chunk = tid >> 4;
    const int sel = blockIdx.x;
    const int b = sel >> 9;                        // 512 blocks/batch
    const size_t slotbase = (size_t)b * Mn + (sel & 511) * 16;

    if (tid == 0) sOkAll = 1;
    if (tid < 16) {
        const float4 qp = qp4[slotbase + tid];
        sX[tid] = qp.x; sQQ[tid] = qp.w;
        sOrig[tid] = qoi[slotbase + tid];
    }
    __syncthreads();

    float xmin = sX[0], xmax = sX[0], qqmax = sQQ[0];
#pragma unroll
    for (int i = 1; i < 16; ++i) {
        xmin = fminf(xmin, sX[i]); xmax = fmaxf(xmax, sX[i]);
        qqmax = fmaxf(qqmax, sQQ[i]);
    }

    const float4 qp = qp4[slotbase + qloc];
    const float q0 = qp.x, q1 = qp.y, q2 = qp.z, qq = qp.w;

    const float4* __restrict__ cp = spos4 + (size_t)b * Nn;
    const int*    __restrict__ ci = sidxp + (size_t)b * Nn;
    const int*    __restrict__ cs = cellS + b * (PB + 1);

    float W = 0.21f * expf(qqmax * (1.0f / 6.0f)) + 0.04f;
    int blo = pbucket(xmin - W), bhi = pbucket(xmax + W);
    int ws = cs[blo], we = cs[bhi + 1];

    double kA = (double)INFINITY, kB = (double)INFINITY, kC = (double)INFINITY;
    SCAN_RANGE(ws, we)

    for (;;) {
        sKey[chunk][0][qloc] = kA;
        sKey[chunk][1][qloc] = kB;
        sKey[chunk][2][qloc] = kC;
        __syncthreads();
        if (tid < 16) {
            double mA = (double)INFINITY, mB = (double)INFINITY, mC = (double)INFINITY;
#pragma unroll
            for (int c = 0; c < 16; ++c)
#pragma unroll
                for (int s = 0; s < 3; ++s) {
                    const double k = sKey[c][s][tid];
                    INSERT3(mA, mB, mC, k);
                }
            const long long ba = __double_as_longlong(mA);
            const long long bb = __double_as_longlong(mB);
            const long long bc = __double_as_longlong(mC);
            const float dA = (float)__longlong_as_double(ba & ~0x7FFll);
            const float dB = (float)__longlong_as_double(bb & ~0x7FFll);
            const float dC = (float)__longlong_as_double(bc & ~0x7FFll);
            const float w0 = 1.0f / (fmaxf(dA, 0.0f) + 1e-16f);
            const float w1 = 1.0f / (fmaxf(dB, 0.0f) + 1e-16f);
            const float w2 = 1.0f / (fmaxf(dC, 0.0f) + 1e-16f);
            const float rden = 1.0f / (w0 + w1 + w2);
            sIdx[tid][0] = (int)(ba & 0x7FF);
            sIdx[tid][1] = (int)(bb & 0x7FF);
            sIdx[tid][2] = (int)(bc & 0x7FF);
            sRW[tid][0] = w0 * rden; sRW[tid][1] = w1 * rden; sRW[tid][2] = w2 * rden;
            // verify: unscanned points have |px - qx| >= gap to scanned edge
            const float qx = sX[tid];
            const float gL = (blo > 0)      ? (qx - (GLOX + (float)blo * PDX)) : 1e30f;
            const float gR = (bhi < PB - 1) ? ((GLOX + (float)(bhi + 1) * PDX) - qx) : 1e30f;
            const float g = fmaxf(fminf(gL, gR), 0.0f);
            if (!(dC < g * g - 1e-3f)) atomicAnd(&sOkAll, 0);
        }
        __syncthreads();
        const bool allok = (sOkAll != 0);
        const bool full = (blo == 0 && bhi == PB - 1);
        if (allok || full) break;
        __syncthreads();
        if (tid == 0) sOkAll = 1;
        W *= 1.6f;
        const int nblo = pbucket(xmin - W), nbhi = pbucket(xmax + W);
        const int nws = cs[nblo], nwe = cs[nbhi + 1];
        SCAN_RANGE(nws, ws)
        SCAN_RANGE(we, nwe)
        ws = nws; we = nwe; blo = nblo; bhi = nbhi;
    }

    // h-build: wave w handles queries [w*4, w*4+4); lane covers 4 channels
    const int wave = tid >> 6, lane = tid & 63;
    const size_t ybase = (size_t)b * Nn;
    const float4 b1v = ((const float4*)b1)[lane];
    for (int j = 0; j < 4; ++j) {
        const int lq = wave * 4 + j;
        const int gq = sOrig[lq];
        const int i0 = sIdx[lq][0], i1 = sIdx[lq][1], i2 = sIdx[lq][2];
        const float w0 = sRW[lq][0], w1 = sRW[lq][1], w2 = sRW[lq][2];
        const ushort4 y0 = ((const ushort4*)(Y + (ybase + i0) * HID))[lane];
        const ushort4 y1 = ((const ushort4*)(Y + (ybase + i1) * HID))[lane];
        const ushort4 y2 = ((const ushort4*)(Y + (ybase + i2) * HID))[lane];
        const ushort4 zz = ((const ushort4*)(Z + (size_t)gq * HID))[lane];
        ushort4 ov;
        float v;
        v = fmaf(w2, bf2f(y2.x), fmaf(w1, bf2f(y1.x), w0 * bf2f(y0.x))) + bf2f(zz.x) + b1v.x;
        ov.x = f2bf(fmaxf(v, 0.0f));
        v = fmaf(w2, bf2f(y2.y), fmaf(w1, bf2f(y1.y), w0 * bf2f(y0.y))) + bf2f(zz.y) + b1v.y;
        ov.y = f2bf(fmaxf(v, 0.0f));
        v = fmaf(w2, bf2f(y2.z), fmaf(w1, bf2f(y1.z), w0 * bf2f(y0.z))) + bf2f(zz.z) + b1v.z;
        ov.z = f2bf(fmaxf(v, 0.0f));
        v = fmaf(w2, bf2f(y2.w), fmaf(w1, bf2f(y1.w), w0 * bf2f(y0.w))) + bf2f(zz.w) + b1v.w;
        ov.w = f2bf(fmaxf(v, 0.0f));
        *(ushort4*)(h + (size_t)gq * HID + lane * 4) = ov;
    }
}

// ---------------------------------------------------------------------------
// Kernel 3: out = h @ W2 + b2   (unchanged from R11)
// ---------------------------------------------------------------------------
__global__ __launch_bounds__(256) void gemm2(
    const ushort* __restrict__ h, const ushort* __restrict__ W2T,
    const float* __restrict__ b2, float* __restrict__ out)
{
    __shared__ ushort Ast[128 * 32];
    __shared__ ushort Bst[128 * 32];

    const int tid = threadIdx.x;
    f32x16 acc[2][2];
#pragma unroll
    for (int i = 0; i < 2; ++i)
#pragma unroll
        for (int j = 0; j < 2; ++j)
#pragma unroll
            for (int e = 0; e < 16; ++e) acc[i][j][e] = 0.0f;

    const long rowbase = (long)blockIdx.x * 128;
    gemm_acc128(h, HID, W2T, HID, HID / 32, rowbase, 0, tid, Ast, Bst, acc);

    const int wave = tid >> 6, lane = tid & 63;
    const int wr = wave >> 1, wc = wave & 1;
    const int l31 = lane & 31, kc0 = lane >> 5;
#pragma unroll
    for (int mf = 0; mf < 2; ++mf)
#pragma unroll
        for (int nf = 0; nf < 2; ++nf) {
            const int col = wc * 64 + nf * 32 + l31;
            const float b2v = b2[col];
#pragma unroll
            for (int e = 0; e < 16; ++e) {
                const int rl = wr * 64 + mf * 32 + (e & 3) + ((e >> 2) << 3) + (kc0 << 2);
                out[(rowbase + rl) * COUT + col] = acc[mf][nf][e] + b2v;
            }
        }
}

// ---------------------------------------------------------------------------
extern "C" void kernel_launch(void* const* d_in, const int* in_sizes, int n_in,
                              void* d_out, int out_size, void* d_ws, size_t ws_size,
                              hipStream_t stream)
{
    const float* x        = (const float*)d_in[0];
    const float* pos      = (const float*)d_in[1];
    const float* x_skip   = (const float*)d_in[2];
    const float* pos_skip = (const float*)d_in[3];
    const float* W1       = (const float*)d_in[4];
    const float* b1       = (const float*)d_in[5];
    const float* W2       = (const float*)d_in[6];
    const float* b2       = (const float*)d_in[7];

    float* out = (float*)d_out;

    char* wp = (char*)d_ws;
    ushort* xb   = (ushort*)wp; wp += (size_t)Bn * Nn * CIN * 2;     // 4 MB
    ushort* xsb  = (ushort*)wp; wp += (size_t)Bn * Mn * CSKIP * 2;   // 8 MB
    ushort* Yb   = (ushort*)wp; wp += (size_t)Bn * Nn * HID * 2;     // 4 MB
    ushort* Zb   = (ushort*)wp; wp += (size_t)Bn * Mn * HID * 2;     // 16 MB
    ushort* hb   = (ushort*)wp; wp += (size_t)Bn * Mn * HID * 2;     // 16 MB
    ushort* W1T  = (ushort*)wp; wp += (size_t)HID * KTOT * 2;        // 192 KB
    ushort* W2T  = (ushort*)wp; wp += (size_t)COUT * HID * 2;        // 64 KB
    float4* spos4 = (float4*)wp; wp += (size_t)Bn * Nn * 16;         // 128 KB
    int*    sidxp = (int*)wp;    wp += (size_t)Bn * Nn * 4;          // 32 KB
    int*    cellS = (int*)wp;    wp += (size_t)Bn * (PB + 1) * 4;    // ~4 KB
    float4* qp4   = (float4*)wp; wp += (size_t)Bn * Mn * 16;         // 512 KB
    int*    qoi   = (int*)wp;                                        // 128 KB

    // 0) prep converts + tail + point/query sorts
    prep_sort<<<dim3(6792), 256, 0, stream>>>(
        x, x_skip, pos, pos_skip, W1, W2, xb, xsb, W1T, W2T,
        spos4, sidxp, cellS, qp4, qoi, out + (size_t)Bn * Mn * COUT);

    // 1) Y = xb @ W1[:256], Z = xsb @ W1[256:]
    yz_gemm<<<dim3(640), 256, 0, stream>>>(xb, xsb, W1T, Yb, Zb);

    // 2) windowed KNN select + h = relu(sum w*Y + Z + b1)
    knn_win<<<dim3(2048), 256, 0, stream>>>(
        spos4, sidxp, cellS, qp4, qoi, Yb, Zb, b1, hb);

    // 3) out = h @ W2 + b2
    gemm2<<<dim3(256), 256, 0, stream>>>(hb, W2T, b2, out);
}